// Round 4
// baseline (476.769 us; speedup 1.0000x reference)
//
#include <hip/hip_runtime.h>
#include <hip/hip_bf16.h>

typedef __bf16 bf16x8 __attribute__((ext_vector_type(8)));
typedef __bf16 bf16x4 __attribute__((ext_vector_type(4)));
typedef float  f32x4  __attribute__((ext_vector_type(4)));

// ---- workspace layout (bytes) ----
#define WS_B1T   0         // [512][128] bf16: [Wqkv | Wqg]^T  (n-major)
#define WS_B2T   131072    // [256][128] bf16: [Wout | 0.1*Woutg]^T
#define WS_BIAS1 196608    // f32[512] = [bqkv | bqg]
#define WS_BIAS2 198656    // f32[128] = bout + 0.1*boutg
#define WS_KVG   199168    // f32 kgT[8h][16d][8g] ; vgT at +4096B

// ---------------- prep: fully parallel (57 blocks x 256 threads) ----------------
__global__ __launch_bounds__(256) void wattn_prep(
    const float* __restrict__ Wqkv, const float* __restrict__ bqkv,
    const float* __restrict__ Wout, const float* __restrict__ bout,
    const float* __restrict__ Wqg,  const float* __restrict__ bqg,
    const float* __restrict__ Wkvg, const float* __restrict__ bkvg,
    const float* __restrict__ Woutg,const float* __restrict__ boutg,
    const float* __restrict__ gtok, unsigned char* __restrict__ ws)
{
    const int blk = blockIdx.x, tid = threadIdx.x;
    __bf16* B1t = (__bf16*)(ws + WS_B1T);
    __bf16* B2t = (__bf16*)(ws + WS_B2T);
    float* bias1 = (float*)(ws + WS_BIAS1);
    float* bias2 = (float*)(ws + WS_BIAS2);
    float* kvg   = (float*)(ws + WS_KVG);

    if (blk < 32) {
        #pragma unroll
        for (int j = 0; j < 8; ++j) {
            const int i = blk*2048 + j*256 + tid;
            const int k = i >> 9, n = i & 511;
            const float w = (n < 384) ? Wqkv[k*384 + n] : Wqg[k*128 + (n - 384)];
            B1t[n*128 + k] = (__bf16)w;
        }
    } else if (blk < 48) {
        #pragma unroll
        for (int j = 0; j < 8; ++j) {
            const int i = (blk - 32)*2048 + j*256 + tid;
            const int k = i >> 8, n = i & 255;
            const float w = (n < 128) ? Wout[k*128 + n] : 0.1f * Woutg[k*128 + (n - 128)];
            B2t[n*128 + k] = (__bf16)w;
        }
    } else if (blk < 56) {
        const int g = blk - 48;
        const int j = tid;   // 0..255
        float acc = bkvg[j];
        #pragma unroll 8
        for (int c = 0; c < 128; ++c) acc += gtok[g*128 + c] * Wkvg[c*256 + j];
        kvg[(j >> 7)*1024 + ((j >> 4) & 7)*128 + (j & 15)*8 + g] = acc;
    } else {
        for (int i = tid; i < 512; i += 256) bias1[i] = (i < 384) ? bqkv[i] : bqg[i - 384];
        for (int i = tid; i < 128; i += 256) bias2[i] = bout[i] + 0.1f * boutg[i];
    }
}

// ---------------- fused per-window kernel, 32 KiB LDS ----------------
// One wave per head (8 waves). LDS map:
//   X region  [0,16K):  Phase A/B: features [64t][128c] swz((t&7)<<4)
//                       post-b2 per-wave 2K slice Xh: Q [64][16d] -> P [32][32k]
//                       post-b3: O [64t][128c] (shared)
//   KV region [16K,32K): per-wave 2K slice KVh: K [64][16d] -> V^T [16d][64t] -> qgT
//                       post-b3: G [64t][128c] (shared)
__global__ __launch_bounds__(512, 8) void wattn_main(
    const float* __restrict__ feat,
    const unsigned char* __restrict__ ws,
    float* __restrict__ out)
{
    __shared__ __align__(16) unsigned char lds[32768];
    const int tid  = threadIdx.x;
    const int h    = tid >> 6;    // wave = head
    const int lane = tid & 63;
    const int rg   = lane >> 4;
    const int cl   = lane & 15;

    const int blk = blockIdx.x;
    const int b   = blk >> 9;
    const int rem = blk & 511;
    const int base_row = b*32768 + (rem >> 6)*4096 + ((rem >> 3) & 7)*128 + (rem & 7)*4;

    const uint4 z4i = {0u, 0u, 0u, 0u};
    const bf16x8 zfrag = __builtin_bit_cast(bf16x8, z4i);
    const f32x4 z4 = {0.f, 0.f, 0.f, 0.f};

    unsigned char* Xh  = lds + h*2048;
    unsigned char* KVh = lds + 16384 + h*2048;

    // ---------- Phase A: stage window features as bf16 (swizzled) ----------
    {
        const int row = tid >> 3, j = tid & 7;
        const int grow = base_row + (row >> 4)*1024 + ((row >> 2) & 3)*32 + (row & 3);
        const float* src = feat + grow*128;
        #pragma unroll
        for (int hh = 0; hh < 2; ++hh) {
            const int col = hh*64 + j*8;
            float4 a = *(const float4*)(src + col);
            float4 c = *(const float4*)(src + col + 4);
            bf16x8 v;
            v[0] = (__bf16)a.x; v[1] = (__bf16)a.y; v[2] = (__bf16)a.z; v[3] = (__bf16)a.w;
            v[4] = (__bf16)c.x; v[5] = (__bf16)c.y; v[6] = (__bf16)c.z; v[7] = (__bf16)c.w;
            *(bf16x8*)(lds + ((row*256 + col*2) ^ ((row & 7) << 4))) = v;
        }
    }
    __syncthreads();  // barrier 1

    // ---------- Phase B: [q k v qg] for own head = X @ B1t(+bias) ----------
    f32x4 acc[4][4];
    {
        const __bf16* B1t = (const __bf16*)(ws + WS_B1T);
        const float* bias1 = (const float*)(ws + WS_BIAS1);
        const int ntile[4] = {h, 8 + h, 16 + h, 24 + h};
        #pragma unroll
        for (int i = 0; i < 4; ++i) {
            const float bv = bias1[ntile[i]*16 + cl];
            f32x4 t = {bv, bv, bv, bv};
            #pragma unroll
            for (int mt = 0; mt < 4; ++mt) acc[mt][i] = t;
        }
        #pragma unroll
        for (int ks = 0; ks < 4; ++ks) {
            bf16x8 afr[4];
            #pragma unroll
            for (int mt = 0; mt < 4; ++mt) {
                const int row = mt*16 + cl, col = ks*32 + rg*8;
                afr[mt] = *(const bf16x8*)(lds + ((row*256 + col*2) ^ ((row & 7) << 4)));
            }
            #pragma unroll
            for (int i = 0; i < 4; ++i) {
                bf16x8 bfr = *(const bf16x8*)(B1t + ntile[i]*16*128 + cl*128 + ks*32 + rg*8);
                #pragma unroll
                for (int mt = 0; mt < 4; ++mt)
                    acc[mt][i] = __builtin_amdgcn_mfma_f32_16x16x32_bf16(afr[mt], bfr, acc[mt][i], 0, 0, 0);
            }
        }
    }
    // scatter K into KVh (wave-private; V stays in regs until kf is loaded)
    #pragma unroll
    for (int mt = 0; mt < 4; ++mt)
        #pragma unroll
        for (int r = 0; r < 4; ++r) {
            const int t = mt*16 + rg*4 + r;
            *(__bf16*)(KVh + ((t*32 + cl*2) ^ ((t & 4) << 2))) = (__bf16)acc[mt][1][r];
        }
    __syncthreads();  // barrier 2: X reads done everywhere -> X slices writable

    // scatter Q into Xh (same layout as K)
    #pragma unroll
    for (int mt = 0; mt < 4; ++mt)
        #pragma unroll
        for (int r = 0; r < 4; ++r) {
            const int t = mt*16 + rg*4 + r;
            *(__bf16*)(Xh + ((t*32 + cl*2) ^ ((t & 4) << 2))) = (__bf16)acc[mt][0][r];
        }
    // load kf[4] (K dead after this)
    bf16x8 kf[4];
    #pragma unroll
    for (int kt = 0; kt < 4; ++kt) {
        if (rg < 2) {
            const int row = kt*16 + cl;
            kf[kt] = *(const bf16x8*)(KVh + ((row*32 + rg*16) ^ ((cl & 4) << 2)));
        } else kf[kt] = zfrag;
    }
    // scatter V^T into KVh (overwrites K), [16d][64t] swz((d&7)<<4)
    #pragma unroll
    for (int mt = 0; mt < 4; ++mt) {
        bf16x4 pv;
        #pragma unroll
        for (int r = 0; r < 4; ++r) pv[r] = (__bf16)acc[mt][2][r];
        const int t0 = mt*16 + rg*4;
        *(bf16x4*)(KVh + ((cl*128 + t0*2) ^ ((cl & 7) << 4))) = pv;
    }
    // load qf[4] for all 4 q-tiles (Q dead after this; Xh becomes P buffer)
    bf16x8 qf[4];
    #pragma unroll
    for (int qt = 0; qt < 4; ++qt) {
        if (rg < 2) {
            const int row = qt*16 + cl;
            qf[qt] = *(const bf16x8*)(Xh + ((row*32 + rg*16) ^ ((cl & 4) << 2)));
        } else qf[qt] = zfrag;
    }

    // ---------- Phase C: local attention (wave-private) ----------
    f32x4 o[4] = {z4, z4, z4, z4};
    float rinv[4];
    #pragma unroll
    for (int half = 0; half < 2; ++half) {
        const int q0t = half*2;
        f32x4 s[4][2];
        #pragma unroll
        for (int kt = 0; kt < 4; ++kt)
            #pragma unroll
            for (int i = 0; i < 2; ++i)
                s[kt][i] = __builtin_amdgcn_mfma_f32_16x16x32_bf16(kf[kt], qf[q0t + i], z4, 0, 0, 0);
        // softmax over k
        #pragma unroll
        for (int i = 0; i < 2; ++i) {
            float m = -1e30f;
            #pragma unroll
            for (int kt = 0; kt < 4; ++kt)
                m = fmaxf(m, fmaxf(fmaxf(s[kt][i][0], s[kt][i][1]), fmaxf(s[kt][i][2], s[kt][i][3])));
            m = fmaxf(m, __shfl_xor(m, 16));
            m = fmaxf(m, __shfl_xor(m, 32));
            float sm = 0.f;
            #pragma unroll
            for (int kt = 0; kt < 4; ++kt)
                #pragma unroll
                for (int r = 0; r < 4; ++r) {
                    const float e = __expf((s[kt][i][r] - m) * 0.25f);
                    s[kt][i][r] = e;
                    sm += e;
                }
            sm += __shfl_xor(sm, 16);
            sm += __shfl_xor(sm, 32);
            rinv[q0t + i] = 1.0f / sm;
        }
        // P (unnormalized) -> Xh [32q][64B], then PV per 32-key slab
        #pragma unroll
        for (int sl = 0; sl < 2; ++sl) {
            #pragma unroll
            for (int i = 0; i < 2; ++i) {
                const int q = (q0t + i)*16 + cl;
                unsigned char* Pb = Xh + (q & 31)*64;
                #pragma unroll
                for (int kk = 0; kk < 2; ++kk) {
                    const int kt = sl*2 + kk;
                    bf16x4 pp;
                    #pragma unroll
                    for (int r = 0; r < 4; ++r) pp[r] = (__bf16)s[kt][i][r];
                    *(bf16x4*)(Pb + ((kk*32 + rg*8) ^ ((q & 3) << 4))) = pp;
                }
            }
            const bf16x8 vf = *(const bf16x8*)(KVh + ((cl*128 + sl*64 + rg*16) ^ ((cl & 7) << 4)));
            #pragma unroll
            for (int i = 0; i < 2; ++i) {
                const int q = (q0t + i)*16 + cl;
                const bf16x8 pf = *(const bf16x8*)(Xh + (q & 31)*64 + ((rg*16) ^ ((q & 3) << 4)));
                o[q0t + i] = __builtin_amdgcn_mfma_f32_16x16x32_bf16(vf, pf, o[q0t + i], 0, 0, 0);
            }
        }
    }
    // qgT into KVh (V dead): [16d][64t] swz((d&7)<<4)
    #pragma unroll
    for (int mt = 0; mt < 4; ++mt) {
        bf16x4 pq;
        #pragma unroll
        for (int r = 0; r < 4; ++r) pq[r] = (__bf16)acc[mt][3][r];
        const int t0 = mt*16 + rg*4;
        *(bf16x4*)(KVh + ((cl*128 + t0*2) ^ ((cl & 7) << 4))) = pq;
    }

    // ---------- Phase D: global-token cross attention (lane = token) ----------
    float got[16];
    {
        float qgv[16];
        #pragma unroll
        for (int d = 0; d < 16; ++d)
            qgv[d] = (float)*(const __bf16*)(KVh + ((d*128 + lane*2) ^ ((d & 7) << 4)));
        const float* kgT = (const float*)(ws + WS_KVG) + h*128;
        const float* vgT = kgT + 1024;
        float lg[8] = {0.f,0.f,0.f,0.f,0.f,0.f,0.f,0.f};
        #pragma unroll
        for (int d = 0; d < 16; ++d) {
            const float4 k0 = *(const float4*)(kgT + d*8);
            const float4 k1 = *(const float4*)(kgT + d*8 + 4);
            const float qv = qgv[d];
            lg[0] += qv*k0.x; lg[1] += qv*k0.y; lg[2] += qv*k0.z; lg[3] += qv*k0.w;
            lg[4] += qv*k1.x; lg[5] += qv*k1.y; lg[6] += qv*k1.z; lg[7] += qv*k1.w;
        }
        float m = fmaxf(fmaxf(fmaxf(lg[0], lg[1]), fmaxf(lg[2], lg[3])),
                        fmaxf(fmaxf(lg[4], lg[5]), fmaxf(lg[6], lg[7])));
        float sm = 0.f;
        float p[8];
        #pragma unroll
        for (int g = 0; g < 8; ++g) { p[g] = __expf((lg[g] - m) * 0.25f); sm += p[g]; }
        const float rs = 1.0f / sm;
        #pragma unroll
        for (int g = 0; g < 8; ++g) p[g] *= rs;
        #pragma unroll
        for (int d = 0; d < 16; ++d) {
            const float4 v0 = *(const float4*)(vgT + d*8);
            const float4 v1 = *(const float4*)(vgT + d*8 + 4);
            got[d] = p[0]*v0.x + p[1]*v0.y + p[2]*v0.z + p[3]*v0.w
                   + p[4]*v1.x + p[5]*v1.y + p[6]*v1.z + p[7]*v1.w;
        }
    }
    __syncthreads();  // barrier 3: all P/K/V/qgT consumption done -> shared O/G regions

    // O -> X region [64t][128c] swz((t&7)<<4), fold 1/sum
    #pragma unroll
    for (int qt = 0; qt < 4; ++qt) {
        const int t = qt*16 + cl;
        bf16x4 ov;
        #pragma unroll
        for (int r = 0; r < 4; ++r) ov[r] = (__bf16)(o[qt][r] * rinv[qt]);
        *(bf16x4*)(lds + ((t*256 + h*32 + rg*8) ^ ((t & 7) << 4))) = ov;
    }
    // G -> KV region [64t][128c] swz((t&7)<<4); lane = t
    {
        bf16x8 g0, g1;
        #pragma unroll
        for (int j = 0; j < 8; ++j) { g0[j] = (__bf16)got[j]; g1[j] = (__bf16)got[8 + j]; }
        *(bf16x8*)(lds + 16384 + ((lane*256 + h*32)      ^ ((lane & 7) << 4))) = g0;
        *(bf16x8*)(lds + 16384 + ((lane*256 + h*32 + 16) ^ ((lane & 7) << 4))) = g1;
    }
    __syncthreads();  // barrier 4

    // ---------- Phase E: Y^T = W2t . [O|G]^T ----------
    // wave h: n-tiles {2a, 2a+1} (a=h&3), token-tiles {2bb, 2bb+1} (bb=h>>2)
    // -> each wave's stores cover 128 contiguous bytes per token row.
    {
        const __bf16* B2t = (const __bf16*)(ws + WS_B2T);
        const float* bias2 = (const float*)(ws + WS_BIAS2);
        const int a = h & 3, bb = h >> 2;
        f32x4 y[2][2];
        #pragma unroll
        for (int j = 0; j < 2; ++j) {
            const float4 bv = *(const float4*)(bias2 + (2*a + j)*16 + rg*4);
            #pragma unroll
            for (int i = 0; i < 2; ++i) { f32x4 t = {bv.x, bv.y, bv.z, bv.w}; y[i][j] = t; }
        }
        #pragma unroll
        for (int ks = 0; ks < 4; ++ks) {
            bf16x8 aW[2], aG[2], bO[2], bG[2];
            #pragma unroll
            for (int j = 0; j < 2; ++j) {
                const int n = (2*a + j)*16 + cl;
                aW[j] = *(const bf16x8*)(B2t + n*128 + ks*32 + rg*8);
                aG[j] = *(const bf16x8*)(B2t + (128 + n)*128 + ks*32 + rg*8);
            }
            #pragma unroll
            for (int i = 0; i < 2; ++i) {
                const int t = (2*bb + i)*16 + cl;
                const int off = (t*256 + ks*64 + rg*16) ^ ((t & 7) << 4);
                bO[i] = *(const bf16x8*)(lds + off);
                bG[i] = *(const bf16x8*)(lds + 16384 + off);
            }
            #pragma unroll
            for (int i = 0; i < 2; ++i)
                #pragma unroll
                for (int j = 0; j < 2; ++j) {
                    y[i][j] = __builtin_amdgcn_mfma_f32_16x16x32_bf16(aW[j], bO[i], y[i][j], 0, 0, 0);
                    y[i][j] = __builtin_amdgcn_mfma_f32_16x16x32_bf16(aG[j], bG[i], y[i][j], 0, 0, 0);
                }
        }
        #pragma unroll
        for (int i = 0; i < 2; ++i) {
            const int grow = base_row + (2*bb + i)*1024 + (cl >> 2)*32 + (cl & 3);
            #pragma unroll
            for (int j = 0; j < 2; ++j)
                *(f32x4*)(out + grow*128 + (2*a + j)*16 + rg*4) = y[i][j];
        }
    }
}

extern "C" void kernel_launch(void* const* d_in, const int* in_sizes, int n_in,
                              void* d_out, int out_size, void* d_ws, size_t ws_size,
                              hipStream_t stream) {
    (void)in_sizes; (void)n_in; (void)out_size; (void)ws_size;
    const float* feat  = (const float*)d_in[0];
    const float* Wqkv  = (const float*)d_in[1];
    const float* bqkv  = (const float*)d_in[2];
    const float* Wout  = (const float*)d_in[3];
    const float* bout  = (const float*)d_in[4];
    const float* Wqg   = (const float*)d_in[5];
    const float* bqg   = (const float*)d_in[6];
    const float* Wkvg  = (const float*)d_in[7];
    const float* bkvg  = (const float*)d_in[8];
    const float* Woutg = (const float*)d_in[9];
    const float* boutg = (const float*)d_in[10];
    const float* gtok  = (const float*)d_in[11];
    unsigned char* ws  = (unsigned char*)d_ws;

    wattn_prep<<<dim3(57), dim3(256), 0, stream>>>(
        Wqkv, bqkv, Wout, bout, Wqg, bqg, Wkvg, bkvg, Woutg, boutg, gtok, ws);
    wattn_main<<<dim3(2048), dim3(512), 0, stream>>>(feat, ws, (float*)d_out);
}